// Round 14
// baseline (300.633 us; speedup 1.0000x reference)
//
#include <hip/hip_runtime.h>
#include <stdint.h>

typedef unsigned short u16;
typedef __attribute__((ext_vector_type(8))) short short8;
typedef __attribute__((ext_vector_type(4))) float f32x4;
typedef __attribute__((ext_vector_type(4))) unsigned short u16x4;

#define DEV __device__ __forceinline__

DEV u16 f2bf(float f) {
  union { float f; unsigned u; } v; v.f = f;
  unsigned r = v.u + 0x7fffu + ((v.u >> 16) & 1u);
  return (u16)(r >> 16);
}
DEV float bf2f(u16 b) {
  union { unsigned u; float f; } v; v.u = ((unsigned)b) << 16;
  return v.f;
}
DEV void gload_lds16(const void* g, void* l) {
  __builtin_amdgcn_global_load_lds((const __attribute__((address_space(1))) void*)g,
                                   (__attribute__((address_space(3))) void*)l,
                                   16, 0, 0);
}
// raw barrier: no compiler-inserted vmcnt(0) drain (unlike __syncthreads)
DEV void block_barrier() {
  asm volatile("" ::: "memory");
  __builtin_amdgcn_s_barrier();
  asm volatile("" ::: "memory");
}

// ---------------- fused prep: x->bf16 | W_attn^T | W_proj^T | RoPE table -----
__global__ void k_prep(const float* __restrict__ x, u16* __restrict__ xb,
                       const float* __restrict__ Wa, u16* __restrict__ wqkvT,
                       const float* __restrict__ Wp, u16* __restrict__ wprojT,
                       float* __restrict__ ct, float* __restrict__ st) {
  __shared__ float tile[32][33];
  const int bid = blockIdx.x, tid = threadIdx.x;
  if (bid < 8192) {
    int i = bid * 256 + tid;
    const f32x4 v = *(const f32x4*)(x + (size_t)i * 4);
    u16x4 o;
    o[0] = f2bf(v[0]); o[1] = f2bf(v[1]); o[2] = f2bf(v[2]); o[3] = f2bf(v[3]);
    *(u16x4*)(xb + (size_t)i * 4) = o;
  } else if (bid < 8192 + 12288 + 4096) {
    const bool wa = bid < 8192 + 12288;
    const int b2 = wa ? bid - 8192 : bid - 8192 - 12288;
    const int gw = wa ? 192 : 64;
    const float* in = wa ? Wa : Wp;
    u16* out = wa ? wqkvT : wprojT;
    const int C = wa ? 6144 : 2048;
    const int c0 = (b2 % gw) * 32, r0 = (b2 / gw) * 32;
    const int tx = tid & 31, ty = tid >> 5;
#pragma unroll
    for (int j = 0; j < 32; j += 8)
      tile[ty + j][tx] = in[(size_t)(r0 + ty + j) * C + (c0 + tx)];
    __syncthreads();
#pragma unroll
    for (int j = 0; j < 32; j += 8)
      out[(size_t)(c0 + ty + j) * 2048 + (r0 + tx)] = f2bf(tile[tx][ty + j]);
  } else {
    int id = (bid - 24576) * 256 + tid;
    int t = id >> 6, dd = id & 63;
    float inv = exp2f((float)dd * -0.20762050593045077f);
    float s, c;
    sincosf((float)t * inv, &s, &c);
    ct[id] = c; st[id] = s;
  }
}

// ======== QKV GEMM with fused RoPE/head-split/V-transpose epilogue v3 ========
// (unchanged from round 12)
__global__ __launch_bounds__(512, 2) void k_gemmqkv(const u16* __restrict__ A,
                                                    const u16* __restrict__ Bt,
                                                    const float* __restrict__ bias,
                                                    u16* __restrict__ qh,
                                                    u16* __restrict__ kh,
                                                    u16* __restrict__ vt,
                                                    const float* __restrict__ rtab) {
  const int Kld = 2048, nt = 32;
  __shared__ __align__(16) short smem[4][256 * 64];  // [0..1]=lA dbuf, [2..3]=lB dbuf
  const int tid = threadIdx.x;
  const int wid = tid >> 6, lane = tid & 63;
  const int gx = gridDim.x;
  const int nwg = gx * gridDim.y;
  const int orig = blockIdx.y * gx + blockIdx.x;
  const int lg = (orig & 7) * (nwg >> 3) + (orig >> 3);
  const int bm = (lg % gx) * 256, bn = (lg / gx) * 256;
  const int wr = wid >> 2, wc = wid & 3;            // 2M x 4N wave grid
  const int r = lane & 15, kq = lane >> 4, r7 = lane & 7;

  int aoff[4], boff[4], lbase[4];
#pragma unroll
  for (int j = 0; j < 4; ++j) {
    int c = j * 512 + wid * 64 + lane;
    int row = c >> 3, ch = c & 7;
    aoff[j] = (bm + row) * Kld + (ch ^ (row & 7)) * 8;
    boff[j] = (bn + row) * Kld + (ch ^ (row & 7)) * 8;
    lbase[j] = (j * 512 + wid * 64) * 16;           // wave-uniform LDS byte base
  }

#define STG_A(k0, buf, j) gload_lds16(A + aoff[j] + (k0), (char*)&smem[(buf)][0] + lbase[j])
#define STG_B(k0, buf, j) gload_lds16(Bt + boff[j] + (k0), (char*)&smem[2 + (buf)][0] + lbase[j])
#define RD_A(AF, MH, KK)                                                        \
  _Pragma("unroll")                                                             \
  for (int m2 = 0; m2 < 4; ++m2)                                                \
    AF[m2] = *(const short8*)&As[(wr * 128 + (MH) * 64 + m2 * 16 + r) * 64      \
                                 + (((KK) * 4 + kq) ^ r7) * 8];
#define RD_B(KK)                                                                \
  _Pragma("unroll")                                                             \
  for (int nf = 0; nf < 4; ++nf)                                                \
    bfr[KK][nf] = *(const short8*)&Bs[(wc * 64 + nf * 16 + r) * 64              \
                                      + (((KK) * 4 + kq) ^ r7) * 8];
#define PH_MFMA(AF, MH, KK)                                                     \
  __builtin_amdgcn_s_setprio(1);                                                \
  _Pragma("unroll")                                                             \
  for (int m2 = 0; m2 < 4; ++m2)                                                \
    _Pragma("unroll")                                                           \
    for (int nf = 0; nf < 4; ++nf)                                              \
      acc[(MH) * 4 + m2][nf] = __builtin_amdgcn_mfma_f32_16x16x32_bf16(         \
          AF[m2], bfr[KK][nf], acc[(MH) * 4 + m2][nf], 0, 0, 0);                \
  __builtin_amdgcn_s_setprio(0);

  f32x4 acc[8][4];
  const f32x4 zero = {0.f, 0.f, 0.f, 0.f};
#pragma unroll
  for (int i = 0; i < 8; ++i)
#pragma unroll
    for (int j = 0; j < 4; ++j) acc[i][j] = zero;

#pragma unroll
  for (int j = 0; j < 4; ++j) STG_A(0, 0, j);
#pragma unroll
  for (int j = 0; j < 4; ++j) STG_B(0, 0, j);
#pragma unroll
  for (int j = 0; j < 4; ++j) STG_B(64, 1, j);
  asm volatile("s_waitcnt vmcnt(4)" ::: "memory");
  block_barrier();

#pragma unroll 1
  for (int t = 0; t < nt; ++t) {
    const int cur = t & 1, nxt = cur ^ 1;
    const short* As = &smem[cur][0];
    const short* Bs = &smem[2 + cur][0];
    const int kA = (t + 1) * 64, kB = (t + 2) * 64;
    const bool sA = (t + 1 < nt), sB = (t + 2 < nt);
    short8 bfr[2][4];
    short8 af[4];

    RD_B(0)
    RD_A(af, 0, 0)
    if (sA) { STG_A(kA, nxt, 0); STG_A(kA, nxt, 1); }
    block_barrier();
    PH_MFMA(af, 0, 0)
    block_barrier();

    RD_B(1)
    RD_A(af, 0, 1)
    if (sA) { STG_A(kA, nxt, 2); STG_A(kA, nxt, 3); }
    block_barrier();
    PH_MFMA(af, 0, 1)
    block_barrier();

    RD_A(af, 1, 0)
    if (sB) { STG_B(kB, cur, 0); STG_B(kB, cur, 1); }
    block_barrier();
    PH_MFMA(af, 1, 0)
    block_barrier();

    RD_A(af, 1, 1)
    if (sB) { STG_B(kB, cur, 2); STG_B(kB, cur, 3); }
    block_barrier();
    PH_MFMA(af, 1, 1)
    if (t + 1 < nt) {
      if (sB) asm volatile("s_waitcnt vmcnt(4)" ::: "memory");
      else    asm volatile("s_waitcnt vmcnt(0)" ::: "memory");
    }
    block_barrier();
  }
#undef STG_A
#undef STG_B
#undef RD_A
#undef RD_B
#undef PH_MFMA

  // -------- fused epilogue (LDS-staged, coalesced writes) --------
  const int by = lg / gx;            // 0..23
  const int part = by >> 3;          // 0=q, 1=k, 2=v
  const int b_ = bm >> 11;           // batch
  const int tb = bm & 2047;          // t base (block never crosses batch)
  const int hbase = (bn & 2047) >> 7;
  u16* ob = (u16*)&smem[0][0];       // 128 KB staging [256 ml][256 cl]

#pragma unroll
  for (int nf = 0; nf < 4; ++nf) {
    int nl = wc * 64 + nf * 16 + r;
    float bv = bias[bn + nl];
#pragma unroll
    for (int mf = 0; mf < 8; ++mf) {
      int mlb = wr * 128 + mf * 16 + kq * 4;
#pragma unroll
      for (int i = 0; i < 4; ++i) {
        int ml = mlb + i;
        int cl = (part == 2)
          ? (nl ^ (((ml >> 2) & 3) << 4) ^ (((ml >> 4) & 7) << 1))
          : (nl ^ (((ml >> 2) & 3) << 4));
        ob[ml * 256 + cl] = f2bf(acc[mf][nf][i] + bv);
      }
    }
  }
  block_barrier();

  if (part == 2) {
#pragma unroll 1
    for (int iter = 0; iter < 32; ++iter) {
      int dl = iter * 8 + wid;
      int hh = hbase + (dl >> 7), d = dl & 127;
      int tl4 = lane * 4;
      int cl = dl ^ ((lane & 3) << 4) ^ (((lane >> 2) & 7) << 1);
      u16x4 o;
#pragma unroll
      for (int j = 0; j < 4; ++j) o[j] = ob[(tl4 + j) * 256 + cl];
      *(u16x4*)(vt + ((size_t)(b_ * 16 + hh) * 128 + d) * 2048 + tb + tl4) = o;
    }
  } else {
    u16* dst = part ? kh : qh;
    const float qscale = part ? 1.0f : 0.12751744766834352f;
    const int nl2 = lane * 4;
    const int hh = hbase + (nl2 >> 7);
    const int d0 = nl2 & 127;
    const int hi = (nl2 >> 6) & 1;
    const int dd4 = nl2 & 63;
    const float* ct = rtab;
    const float* st = rtab + 131072;
#pragma unroll 2
    for (int iter = 0; iter < 32; ++iter) {
      int tl = iter * 8 + wid;
      int tg = tb + tl;
      f32x4 c4 = *(const f32x4*)(ct + tg * 64 + dd4);
      f32x4 s4 = *(const f32x4*)(st + tg * 64 + dd4);
      int xr = ((tl >> 2) & 3) << 4;
      int base = tl * 256 + (nl2 ^ xr);
      int pbase = tl * 256 + ((nl2 ^ 64) ^ xr);
      u16x4 o;
#pragma unroll
      for (int j = 0; j < 4; ++j) {
        float vo = bf2f(ob[base + j]);
        float vp = bf2f(ob[pbase + j]);
        float vr = hi ? (vo * c4[j] + vp * s4[j]) : (vo * c4[j] - vp * s4[j]);
        o[j] = f2bf(vr * qscale);
      }
      *(u16x4*)(dst + ((size_t)(b_ * 16 + hh) * 2048 + tg) * 128 + d0) = o;
    }
  }
}

// ---------------- GEMM TN v4 (proj split-K): 256x256, even 4-phase ----------
template <bool OUT_BF16, bool SPLITK>
__global__ __launch_bounds__(512, 2) void k_gemm3(const u16* __restrict__ A,
                                                  const u16* __restrict__ Bt,
                                                  const float* __restrict__ bias,
                                                  void* __restrict__ Cv,
                                                  int M, int N, int Kld, int nkt) {
  __shared__ __align__(16) short lA[2][256 * 64];   // 2 x 32 KB
  __shared__ __align__(16) short lB[2][256 * 64];   // 2 x 32 KB
  const int tid = threadIdx.x;
  const int wid = tid >> 6, lane = tid & 63;
  const int gx = gridDim.x;
  const int nwg = gx * gridDim.y;
  const int orig = blockIdx.y * gx + blockIdx.x;
  const int lg = (orig & 7) * (nwg >> 3) + (orig >> 3);
  const int bm = (lg % gx) * 256, bn = (lg / gx) * 256;
  const int wr = wid >> 2, wc = wid & 3;            // 2M x 4N wave grid
  const int r = lane & 15, kq = lane >> 4, r7 = lane & 7;
  const int kz = SPLITK ? blockIdx.z * (nkt << 6) : 0;

  int aoff[4], boff[4], lbase[4];
#pragma unroll
  for (int j = 0; j < 4; ++j) {
    int c = j * 512 + wid * 64 + lane;
    int row = c >> 3, ch = c & 7;
    aoff[j] = (bm + row) * Kld + kz + (ch ^ (row & 7)) * 8;
    boff[j] = (bn + row) * Kld + kz + (ch ^ (row & 7)) * 8;
    lbase[j] = (j * 512 + wid * 64) * 16;           // wave-uniform LDS byte base
  }

#define STG_A(k0, buf, j) gload_lds16(A + aoff[j] + (k0), (char*)&lA[(buf)][0] + lbase[j])
#define STG_B(k0, buf, j) gload_lds16(Bt + boff[j] + (k0), (char*)&lB[(buf)][0] + lbase[j])
#define RD_A(AF, MH, KK)                                                        \
  _Pragma("unroll")                                                             \
  for (int m2 = 0; m2 < 4; ++m2)                                                \
    AF[m2] = *(const short8*)&As[(wr * 128 + (MH) * 64 + m2 * 16 + r) * 64      \
                                 + (((KK) * 4 + kq) ^ r7) * 8];
#define RD_B(KK)                                                                \
  _Pragma("unroll")                                                             \
  for (int nf = 0; nf < 4; ++nf)                                                \
    bfr[KK][nf] = *(const short8*)&Bs[(wc * 64 + nf * 16 + r) * 64              \
                                      + (((KK) * 4 + kq) ^ r7) * 8];
#define PH_MFMA(AF, MH, KK)                                                     \
  __builtin_amdgcn_s_setprio(1);                                                \
  _Pragma("unroll")                                                             \
  for (int m2 = 0; m2 < 4; ++m2)                                                \
    _Pragma("unroll")                                                           \
    for (int nf = 0; nf < 4; ++nf)                                              \
      acc[(MH) * 4 + m2][nf] = __builtin_amdgcn_mfma_f32_16x16x32_bf16(         \
          AF[m2], bfr[KK][nf], acc[(MH) * 4 + m2][nf], 0, 0, 0);                \
  __builtin_amdgcn_s_setprio(0);

  f32x4 acc[8][4];
  const f32x4 zero = {0.f, 0.f, 0.f, 0.f};
#pragma unroll
  for (int i = 0; i < 8; ++i)
#pragma unroll
    for (int j = 0; j < 4; ++j) acc[i][j] = zero;

  const int nt = nkt;

#pragma unroll
  for (int j = 0; j < 4; ++j) STG_A(0, 0, j);
#pragma unroll
  for (int j = 0; j < 4; ++j) STG_B(0, 0, j);
  if (nt > 1) {
#pragma unroll
    for (int j = 0; j < 4; ++j) STG_B(64, 1, j);
    asm volatile("s_waitcnt vmcnt(4)" ::: "memory");
  } else {
    asm volatile("s_waitcnt vmcnt(0)" ::: "memory");
  }
  block_barrier();

#pragma unroll 1
  for (int t = 0; t < nt; ++t) {
    const int cur = t & 1, nxt = cur ^ 1;
    const short* As = &lA[cur][0];
    const short* Bs = &lB[cur][0];
    const int kA = (t + 1) * 64, kB = (t + 2) * 64;
    const bool sA = (t + 1 < nt), sB = (t + 2 < nt);
    short8 bfr[2][4];
    short8 af[4];

    RD_B(0)
    RD_A(af, 0, 0)
    if (sA) { STG_A(kA, nxt, 0); STG_A(kA, nxt, 1); }
    block_barrier();
    PH_MFMA(af, 0, 0)
    block_barrier();

    RD_B(1)
    RD_A(af, 0, 1)
    if (sA) { STG_A(kA, nxt, 2); STG_A(kA, nxt, 3); }
    block_barrier();
    PH_MFMA(af, 0, 1)
    block_barrier();

    RD_A(af, 1, 0)
    if (sB) { STG_B(kB, cur, 0); STG_B(kB, cur, 1); }
    block_barrier();
    PH_MFMA(af, 1, 0)
    block_barrier();

    RD_A(af, 1, 1)
    if (sB) { STG_B(kB, cur, 2); STG_B(kB, cur, 3); }
    block_barrier();
    PH_MFMA(af, 1, 1)
    if (t + 1 < nt) {
      if (sB) asm volatile("s_waitcnt vmcnt(4)" ::: "memory");
      else    asm volatile("s_waitcnt vmcnt(0)" ::: "memory");
    }
    block_barrier();
  }
#undef STG_A
#undef STG_B
#undef RD_A
#undef RD_B
#undef PH_MFMA

#pragma unroll
  for (int mf = 0; mf < 8; ++mf)
#pragma unroll
    for (int nf = 0; nf < 4; ++nf) {
      int n = bn + wc * 64 + nf * 16 + r;
      float bv = SPLITK ? 0.f : bias[n];
#pragma unroll
      for (int i = 0; i < 4; ++i) {
        int m = bm + wr * 128 + mf * 16 + kq * 4 + i;
        float val = acc[mf][nf][i] + bv;
        if (SPLITK)
          ((float*)Cv)[(size_t)blockIdx.z * M * N + (size_t)m * N + n] = val;
        else if (OUT_BF16)
          ((u16*)Cv)[(size_t)m * N + n] = f2bf(val);
        else
          ((float*)Cv)[(size_t)m * N + n] = val;
      }
    }
}

// ---------------- split-K reduce: y = p0 + p1 + bias (fp32, N=2048) ----------
__global__ void k_fadd(const float* __restrict__ p, const float* __restrict__ bias,
                       float* __restrict__ y, int n4) {
  const int half4 = 2097152;  // 4096*2048/4
  for (int i = blockIdx.x * blockDim.x + threadIdx.x; i < n4; i += gridDim.x * blockDim.x) {
    f32x4 a = *(const f32x4*)(p + (size_t)i * 4);
    f32x4 b = *(const f32x4*)(p + (size_t)(i + half4) * 4);
    f32x4 bv = *(const f32x4*)(bias + ((i & 511) << 2));
    f32x4 o = a + b + bv;
    *(f32x4*)(y + (size_t)i * 4) = o;
  }
}

// ---------------- causal flash attention v8: swapped QK^T (T12) --------------
// v7 structure (QBLK=128, 4 waves, 2 blocks/CU, co-resident J pairing) with
// S computed as mfma(K,Q) -> S^T: lane holds q-row (mf*16+r, LANE-LOCAL) and
// keys kq*4+i. P-pack via v_cvt_pk_bf16_f32: 8 ds_write_b64 replace 32
// ds_write_b16 + 32 f2bf. lP granule swizzle g^=(r&7)<<1 (8B granules):
// writes 4/bank, b128 reads 8/bank -- both optimal. Row sums lane-local
// (lp[mf] scalar; one xor16+xor32 reduce at end; inv via width-16 shfl).
// T5 setprio around both MFMA clusters.
__global__ __launch_bounds__(256) void k_attn(const u16* __restrict__ qh,
                                              const u16* __restrict__ kh,
                                              const u16* __restrict__ vt,
                                              u16* __restrict__ out) {
  __shared__ __align__(16) short lK[2][64 * 128];   // 32 KB
  __shared__ __align__(16) short lV[2][128 * 64];   // 32 KB
  __shared__ __align__(16) short lP[128 * 64];      // 16 KB (wave-private rows)
  const int tid = threadIdx.x, wid = tid >> 6, lane = tid & 63;
  const int id = blockIdx.x;
  const int jr = id & 15;
  const int J = (id < 256) ? jr : 15 - jr;
  const int h = (id >> 4) & 15, b = id >> 8;
  const int q0 = J * 128;
  const int nkt = 2 * J + 2;
  const size_t bh = (size_t)b * 16 + h;
  const u16* qb = qh + bh * 2048 * 128;
  const u16* kb = kh + bh * 2048 * 128;
  const u16* vb = vt + bh * 128 * 2048;
  const int r = lane & 15, kq = lane >> 4;
  const int r7 = r & 7;
  const int wrow = wid * 32;                        // wave's 32-row band

  int koff[4], voff[4];
#pragma unroll
  for (int i = 0; i < 4; ++i) {
    int ci = (wid * 4 + i) * 64 + lane;
    int krow = ci >> 4, kch = ci & 15;          // K tile: 64 rows x 16 chunks(16B)
    koff[i] = krow * 128 + ((kch ^ (krow & 7)) * 8);
    int vrow = ci >> 3, vch = ci & 7;           // V tile: 128 rows x 8 chunks(16B)
    voff[i] = vrow * 2048 + ((vch ^ (vrow & 7)) * 8);
  }

  // Q fragments (2 mf bands x 4 k-slices), q pre-scaled
  short8 qa[2][4];
#pragma unroll
  for (int mf = 0; mf < 2; ++mf)
#pragma unroll
    for (int kk = 0; kk < 4; ++kk)
      qa[mf][kk] = *(const short8*)(qb + (size_t)(q0 + wrow + mf * 16 + r) * 128 + kk * 32 + kq * 8);

  f32x4 O[2][8];
  const f32x4 zero = {0.f, 0.f, 0.f, 0.f};
#pragma unroll
  for (int mf = 0; mf < 2; ++mf)
#pragma unroll
    for (int nf = 0; nf < 8; ++nf) O[mf][nf] = zero;
  float lp[2] = {0.f, 0.f};   // lane-local row-sum partials (q-row = mf*16+r)

  // prologue stage tile 0 -> buf 0
#pragma unroll
  for (int i = 0; i < 4; ++i) {
    gload_lds16(kb + koff[i], (char*)&lK[0][0] + (wid * 4 + i) * 1024);
    gload_lds16(vb + voff[i], (char*)&lV[0][0] + (wid * 4 + i) * 1024);
  }

#pragma unroll 1
  for (int kt = 0; kt < nkt; ++kt) {
    const int cur = kt & 1;
    if (kt + 1 < nkt) {
      const size_t kbase = (size_t)(kt + 1) * 8192, vbase = (size_t)(kt + 1) * 64;
#pragma unroll
      for (int i = 0; i < 4; ++i) {
        gload_lds16(kb + kbase + koff[i], (char*)&lK[cur ^ 1][0] + (wid * 4 + i) * 1024);
        gload_lds16(vb + vbase + voff[i], (char*)&lV[cur ^ 1][0] + (wid * 4 + i) * 1024);
      }
      asm volatile("s_waitcnt vmcnt(8)" ::: "memory");  // tile kt landed; kt+1 in flight
    } else {
      asm volatile("s_waitcnt vmcnt(0)" ::: "memory");
    }
    block_barrier();

    // S^T = K @ Q^T : S[mf][nf][i] = score(q-row q0+wrow+mf*16+r,
    //                                      key kt*64+nf*16+kq*4+i)
    f32x4 S[2][4];
#pragma unroll
    for (int mf = 0; mf < 2; ++mf)
#pragma unroll
      for (int nf = 0; nf < 4; ++nf) S[mf][nf] = zero;
#pragma unroll
    for (int kk = 0; kk < 4; ++kk) {
      short8 kf[4];
#pragma unroll
      for (int nf = 0; nf < 4; ++nf)
        kf[nf] = *(const short8*)&lK[cur][(nf * 16 + r) * 128 + ((kk * 4 + kq) ^ r7) * 8];
      __builtin_amdgcn_s_setprio(1);
#pragma unroll
      for (int mf = 0; mf < 2; ++mf)
#pragma unroll
        for (int nf = 0; nf < 4; ++nf)
          S[mf][nf] = __builtin_amdgcn_mfma_f32_16x16x32_bf16(kf[nf], qa[mf][kk], S[mf][nf], 0, 0, 0);
      __builtin_amdgcn_s_setprio(0);
    }

    // P = exp2(S) un-normalized; pack pairs via cvt_pk; 8 b64 LDS writes.
    const bool diag = (kt >= nkt - 2);
#pragma unroll
    for (int mf = 0; mf < 2; ++mf) {
      const int rl = wrow + mf * 16 + r;
#pragma unroll
      for (int nf = 0; nf < 4; ++nf) {
        float pv4[4];
#pragma unroll
        for (int i = 0; i < 4; ++i) {
          float pv = exp2f(S[mf][nf][i]);
          if (diag) {
            int kg = kt * 64 + nf * 16 + kq * 4 + i;
            int qg = q0 + wrow + mf * 16 + r;
            pv = (kg > qg) ? 0.f : pv;
          }
          lp[mf] += pv;
          pv4[i] = pv;
        }
        unsigned d0, d1;
        asm("v_cvt_pk_bf16_f32 %0, %1, %2" : "=v"(d0) : "v"(pv4[0]), "v"(pv4[1]));
        asm("v_cvt_pk_bf16_f32 %0, %1, %2" : "=v"(d1) : "v"(pv4[2]), "v"(pv4[3]));
        int g = (nf * 4 + kq) ^ (r7 << 1);
        *(uint2*)((char*)lP + rl * 128 + g * 8) = make_uint2(d0, d1);
      }
    }

    // O += P @ V^T  (P read back per 8-key granule pair, swizzle-matched)
#pragma unroll
    for (int kk = 0; kk < 2; ++kk) {
      short8 pa[2];
#pragma unroll
      for (int mf = 0; mf < 2; ++mf) {
        int rl = wrow + mf * 16 + r;
        int g = (kk * 8 + kq * 2) ^ (r7 << 1);
        pa[mf] = *(const short8*)((const char*)lP + rl * 128 + g * 8);
      }
#pragma unroll
      for (int nf = 0; nf < 8; ++nf) {
        short8 vf = *(const short8*)&lV[cur][(nf * 16 + r) * 64 + ((kk * 4 + kq) ^ r7) * 8];
        __builtin_amdgcn_s_setprio(1);
#pragma unroll
        for (int mf = 0; mf < 2; ++mf)
          O[mf][nf] = __builtin_amdgcn_mfma_f32_16x16x32_bf16(pa[mf], vf, O[mf][nf], 0, 0, 0);
        __builtin_amdgcn_s_setprio(0);
      }
    }
    asm volatile("s_waitcnt lgkmcnt(0)" ::: "memory");
    block_barrier();  // all reads done before next stage overwrites
  }

  // finalize: reduce row sums across kq groups (lanes r, r+16, r+32, r+48)
#pragma unroll
  for (int mf = 0; mf < 2; ++mf) {
    float v = lp[mf];
    v += __shfl_xor(v, 16);
    v += __shfl_xor(v, 32);
    lp[mf] = v;               // all lanes now hold sum for q-row wrow+mf*16+r
  }
  // O layout: q-row = wrow+mf*16+kq*4+i, d = nf*16+r -> fetch inv via shfl
#pragma unroll
  for (int mf = 0; mf < 2; ++mf) {
    float inv[4];
#pragma unroll
    for (int i = 0; i < 4; ++i)
      inv[i] = 1.f / __shfl(lp[mf], kq * 4 + i, 16);
#pragma unroll
    for (int nf = 0; nf < 8; ++nf)
#pragma unroll
      for (int i = 0; i < 4; ++i) {
        int qg = q0 + wrow + mf * 16 + kq * 4 + i;
        out[(size_t)(b * 2048 + qg) * 2048 + h * 128 + nf * 16 + r] = f2bf(O[mf][nf][i] * inv[i]);
      }
  }
}

extern "C" void kernel_launch(void* const* d_in, const int* in_sizes, int n_in,
                              void* d_out, int out_size, void* d_ws, size_t ws_size,
                              hipStream_t stream) {
  const float* x      = (const float*)d_in[0];
  const float* W_attn = (const float*)d_in[1];
  const float* b_attn = (const float*)d_in[2];
  const float* W_proj = (const float*)d_in[3];
  const float* b_proj = (const float*)d_in[4];
  float* y = (float*)d_out;

  // workspace carve-up (bf16 buffers), total 160 MB
  u16* xb     = (u16*)d_ws;                      // [4096][2048]   MB  0-16
  u16* wqkvT  = xb     + (size_t)4096 * 2048;    // [6144][2048]   MB 16-40
  u16* wprojT = wqkvT  + (size_t)6144 * 2048;    // [2048][2048]   MB 40-48
  u16* qkv    = wprojT + (size_t)2048 * 2048;    // (free region)  MB 48-96
  u16* qh     = qkv    + (size_t)4096 * 6144;    // [32][2048][128] 96-112
  u16* kh     = qh     + (size_t)4096 * 2048;    //               112-128
  u16* vt     = kh     + (size_t)4096 * 2048;    // [32][128][2048] 128-144
  u16* attout = vt     + (size_t)4096 * 2048;    // [4096][2048]  144-160
  if (ws_size < (size_t)83886080 * 2) return;    // need 160 MB

  // free-region aliases: RoPE table (1 MB, used only by k_gemmqkv) then
  // proj split-K fp32 partials (64 MB, used after attn)
  float* rtab  = (float*)qkv;
  float* pproj = (float*)qkv;

  k_prep<<<25088, 256, 0, stream>>>(x, xb, W_attn, wqkvT, W_proj, wprojT, rtab, rtab + 131072);
  k_gemmqkv<<<dim3(16, 24), 512, 0, stream>>>(xb, wqkvT, b_attn, qh, kh, vt, rtab);
  k_attn<<<512, 256, 0, stream>>>(qh, kh, vt, attout);
  k_gemm3<false, true><<<dim3(16, 8, 2), 512, 0, stream>>>(attout, wprojT, b_proj, pproj, 4096, 2048, 2048, 16);
  k_fadd<<<2048, 256, 0, stream>>>(pproj, b_proj, y, 2097152);
}

// Round 15
// 291.541 us; speedup vs baseline: 1.0312x; 1.0312x over previous
//
#include <hip/hip_runtime.h>
#include <stdint.h>

typedef unsigned short u16;
typedef __attribute__((ext_vector_type(8))) short short8;
typedef __attribute__((ext_vector_type(4))) float f32x4;
typedef __attribute__((ext_vector_type(4))) unsigned short u16x4;

#define DEV __device__ __forceinline__

DEV u16 f2bf(float f) {
  union { float f; unsigned u; } v; v.f = f;
  unsigned r = v.u + 0x7fffu + ((v.u >> 16) & 1u);
  return (u16)(r >> 16);
}
DEV float bf2f(u16 b) {
  union { unsigned u; float f; } v; v.u = ((unsigned)b) << 16;
  return v.f;
}
DEV void gload_lds16(const void* g, void* l) {
  __builtin_amdgcn_global_load_lds((const __attribute__((address_space(1))) void*)g,
                                   (__attribute__((address_space(3))) void*)l,
                                   16, 0, 0);
}
// raw barrier: no compiler-inserted vmcnt(0) drain (unlike __syncthreads)
DEV void block_barrier() {
  asm volatile("" ::: "memory");
  __builtin_amdgcn_s_barrier();
  asm volatile("" ::: "memory");
}

// ---------------- fused prep: x->bf16 | W_attn^T | W_proj^T | RoPE table -----
__global__ void k_prep(const float* __restrict__ x, u16* __restrict__ xb,
                       const float* __restrict__ Wa, u16* __restrict__ wqkvT,
                       const float* __restrict__ Wp, u16* __restrict__ wprojT,
                       float* __restrict__ ct, float* __restrict__ st) {
  __shared__ float tile[32][33];
  const int bid = blockIdx.x, tid = threadIdx.x;
  if (bid < 8192) {
    int i = bid * 256 + tid;
    const f32x4 v = *(const f32x4*)(x + (size_t)i * 4);
    u16x4 o;
    o[0] = f2bf(v[0]); o[1] = f2bf(v[1]); o[2] = f2bf(v[2]); o[3] = f2bf(v[3]);
    *(u16x4*)(xb + (size_t)i * 4) = o;
  } else if (bid < 8192 + 12288 + 4096) {
    const bool wa = bid < 8192 + 12288;
    const int b2 = wa ? bid - 8192 : bid - 8192 - 12288;
    const int gw = wa ? 192 : 64;
    const float* in = wa ? Wa : Wp;
    u16* out = wa ? wqkvT : wprojT;
    const int C = wa ? 6144 : 2048;
    const int c0 = (b2 % gw) * 32, r0 = (b2 / gw) * 32;
    const int tx = tid & 31, ty = tid >> 5;
#pragma unroll
    for (int j = 0; j < 32; j += 8)
      tile[ty + j][tx] = in[(size_t)(r0 + ty + j) * C + (c0 + tx)];
    __syncthreads();
#pragma unroll
    for (int j = 0; j < 32; j += 8)
      out[(size_t)(c0 + ty + j) * 2048 + (r0 + tx)] = f2bf(tile[tx][ty + j]);
  } else {
    int id = (bid - 24576) * 256 + tid;
    int t = id >> 6, dd = id & 63;
    float inv = exp2f((float)dd * -0.20762050593045077f);
    float s, c;
    sincosf((float)t * inv, &s, &c);
    ct[id] = c; st[id] = s;
  }
}

// ======== QKV GEMM with fused RoPE/head-split/V-transpose epilogue v3 ========
// (unchanged from round 12)
__global__ __launch_bounds__(512, 2) void k_gemmqkv(const u16* __restrict__ A,
                                                    const u16* __restrict__ Bt,
                                                    const float* __restrict__ bias,
                                                    u16* __restrict__ qh,
                                                    u16* __restrict__ kh,
                                                    u16* __restrict__ vt,
                                                    const float* __restrict__ rtab) {
  const int Kld = 2048, nt = 32;
  __shared__ __align__(16) short smem[4][256 * 64];  // [0..1]=lA dbuf, [2..3]=lB dbuf
  const int tid = threadIdx.x;
  const int wid = tid >> 6, lane = tid & 63;
  const int gx = gridDim.x;
  const int nwg = gx * gridDim.y;
  const int orig = blockIdx.y * gx + blockIdx.x;
  const int lg = (orig & 7) * (nwg >> 3) + (orig >> 3);
  const int bm = (lg % gx) * 256, bn = (lg / gx) * 256;
  const int wr = wid >> 2, wc = wid & 3;            // 2M x 4N wave grid
  const int r = lane & 15, kq = lane >> 4, r7 = lane & 7;

  int aoff[4], boff[4], lbase[4];
#pragma unroll
  for (int j = 0; j < 4; ++j) {
    int c = j * 512 + wid * 64 + lane;
    int row = c >> 3, ch = c & 7;
    aoff[j] = (bm + row) * Kld + (ch ^ (row & 7)) * 8;
    boff[j] = (bn + row) * Kld + (ch ^ (row & 7)) * 8;
    lbase[j] = (j * 512 + wid * 64) * 16;           // wave-uniform LDS byte base
  }

#define STG_A(k0, buf, j) gload_lds16(A + aoff[j] + (k0), (char*)&smem[(buf)][0] + lbase[j])
#define STG_B(k0, buf, j) gload_lds16(Bt + boff[j] + (k0), (char*)&smem[2 + (buf)][0] + lbase[j])
#define RD_A(AF, MH, KK)                                                        \
  _Pragma("unroll")                                                             \
  for (int m2 = 0; m2 < 4; ++m2)                                                \
    AF[m2] = *(const short8*)&As[(wr * 128 + (MH) * 64 + m2 * 16 + r) * 64      \
                                 + (((KK) * 4 + kq) ^ r7) * 8];
#define RD_B(KK)                                                                \
  _Pragma("unroll")                                                             \
  for (int nf = 0; nf < 4; ++nf)                                                \
    bfr[KK][nf] = *(const short8*)&Bs[(wc * 64 + nf * 16 + r) * 64              \
                                      + (((KK) * 4 + kq) ^ r7) * 8];
#define PH_MFMA(AF, MH, KK)                                                     \
  __builtin_amdgcn_s_setprio(1);                                                \
  _Pragma("unroll")                                                             \
  for (int m2 = 0; m2 < 4; ++m2)                                                \
    _Pragma("unroll")                                                           \
    for (int nf = 0; nf < 4; ++nf)                                              \
      acc[(MH) * 4 + m2][nf] = __builtin_amdgcn_mfma_f32_16x16x32_bf16(         \
          AF[m2], bfr[KK][nf], acc[(MH) * 4 + m2][nf], 0, 0, 0);                \
  __builtin_amdgcn_s_setprio(0);

  f32x4 acc[8][4];
  const f32x4 zero = {0.f, 0.f, 0.f, 0.f};
#pragma unroll
  for (int i = 0; i < 8; ++i)
#pragma unroll
    for (int j = 0; j < 4; ++j) acc[i][j] = zero;

#pragma unroll
  for (int j = 0; j < 4; ++j) STG_A(0, 0, j);
#pragma unroll
  for (int j = 0; j < 4; ++j) STG_B(0, 0, j);
#pragma unroll
  for (int j = 0; j < 4; ++j) STG_B(64, 1, j);
  asm volatile("s_waitcnt vmcnt(4)" ::: "memory");
  block_barrier();

#pragma unroll 1
  for (int t = 0; t < nt; ++t) {
    const int cur = t & 1, nxt = cur ^ 1;
    const short* As = &smem[cur][0];
    const short* Bs = &smem[2 + cur][0];
    const int kA = (t + 1) * 64, kB = (t + 2) * 64;
    const bool sA = (t + 1 < nt), sB = (t + 2 < nt);
    short8 bfr[2][4];
    short8 af[4];

    RD_B(0)
    RD_A(af, 0, 0)
    if (sA) { STG_A(kA, nxt, 0); STG_A(kA, nxt, 1); }
    block_barrier();
    PH_MFMA(af, 0, 0)
    block_barrier();

    RD_B(1)
    RD_A(af, 0, 1)
    if (sA) { STG_A(kA, nxt, 2); STG_A(kA, nxt, 3); }
    block_barrier();
    PH_MFMA(af, 0, 1)
    block_barrier();

    RD_A(af, 1, 0)
    if (sB) { STG_B(kB, cur, 0); STG_B(kB, cur, 1); }
    block_barrier();
    PH_MFMA(af, 1, 0)
    block_barrier();

    RD_A(af, 1, 1)
    if (sB) { STG_B(kB, cur, 2); STG_B(kB, cur, 3); }
    block_barrier();
    PH_MFMA(af, 1, 1)
    if (t + 1 < nt) {
      if (sB) asm volatile("s_waitcnt vmcnt(4)" ::: "memory");
      else    asm volatile("s_waitcnt vmcnt(0)" ::: "memory");
    }
    block_barrier();
  }
#undef STG_A
#undef STG_B
#undef RD_A
#undef RD_B
#undef PH_MFMA

  // -------- fused epilogue (LDS-staged, coalesced writes) --------
  const int by = lg / gx;            // 0..23
  const int part = by >> 3;          // 0=q, 1=k, 2=v
  const int b_ = bm >> 11;           // batch
  const int tb = bm & 2047;          // t base (block never crosses batch)
  const int hbase = (bn & 2047) >> 7;
  u16* ob = (u16*)&smem[0][0];       // 128 KB staging [256 ml][256 cl]

#pragma unroll
  for (int nf = 0; nf < 4; ++nf) {
    int nl = wc * 64 + nf * 16 + r;
    float bv = bias[bn + nl];
#pragma unroll
    for (int mf = 0; mf < 8; ++mf) {
      int mlb = wr * 128 + mf * 16 + kq * 4;
#pragma unroll
      for (int i = 0; i < 4; ++i) {
        int ml = mlb + i;
        int cl = (part == 2)
          ? (nl ^ (((ml >> 2) & 3) << 4) ^ (((ml >> 4) & 7) << 1))
          : (nl ^ (((ml >> 2) & 3) << 4));
        ob[ml * 256 + cl] = f2bf(acc[mf][nf][i] + bv);
      }
    }
  }
  block_barrier();

  if (part == 2) {
#pragma unroll 1
    for (int iter = 0; iter < 32; ++iter) {
      int dl = iter * 8 + wid;
      int hh = hbase + (dl >> 7), d = dl & 127;
      int tl4 = lane * 4;
      int cl = dl ^ ((lane & 3) << 4) ^ (((lane >> 2) & 7) << 1);
      u16x4 o;
#pragma unroll
      for (int j = 0; j < 4; ++j) o[j] = ob[(tl4 + j) * 256 + cl];
      *(u16x4*)(vt + ((size_t)(b_ * 16 + hh) * 128 + d) * 2048 + tb + tl4) = o;
    }
  } else {
    u16* dst = part ? kh : qh;
    const float qscale = part ? 1.0f : 0.12751744766834352f;
    const int nl2 = lane * 4;
    const int hh = hbase + (nl2 >> 7);
    const int d0 = nl2 & 127;
    const int hi = (nl2 >> 6) & 1;
    const int dd4 = nl2 & 63;
    const float* ct = rtab;
    const float* st = rtab + 131072;
#pragma unroll 2
    for (int iter = 0; iter < 32; ++iter) {
      int tl = iter * 8 + wid;
      int tg = tb + tl;
      f32x4 c4 = *(const f32x4*)(ct + tg * 64 + dd4);
      f32x4 s4 = *(const f32x4*)(st + tg * 64 + dd4);
      int xr = ((tl >> 2) & 3) << 4;
      int base = tl * 256 + (nl2 ^ xr);
      int pbase = tl * 256 + ((nl2 ^ 64) ^ xr);
      u16x4 o;
#pragma unroll
      for (int j = 0; j < 4; ++j) {
        float vo = bf2f(ob[base + j]);
        float vp = bf2f(ob[pbase + j]);
        float vr = hi ? (vo * c4[j] + vp * s4[j]) : (vo * c4[j] - vp * s4[j]);
        o[j] = f2bf(vr * qscale);
      }
      *(u16x4*)(dst + ((size_t)(b_ * 16 + hh) * 2048 + tg) * 128 + d0) = o;
    }
  }
}

// ---------------- proj GEMM: y = attout @ wprojT^T + bias, full K ------------
// BM=256, BN=128, BK=64, nt=32. Grid (16,16) = 256 blocks = exactly 1 round
// (replaces split-K + fadd: no 64 MB fp32 partial round-trip, one launch).
// 8 waves (4M x 2N), wave-tile 64x64 (acc 64 VGPR). Same 4-phase counted-vmcnt
// schedule; staging A(t+1)@p0/p1 (4 calls), B(t+2)@p2/p3 (2 calls); boundary
// vmcnt(2): in-order retire lands B(t+1),A(t+1), leaves B(t+2) in flight.
__global__ __launch_bounds__(512, 2) void k_proj(const u16* __restrict__ A,
                                                 const u16* __restrict__ Bt,
                                                 const float* __restrict__ bias,
                                                 float* __restrict__ y) {
  const int Kld = 2048, nt = 32;
  __shared__ __align__(16) short lA[2][256 * 64];   // 2 x 32 KB
  __shared__ __align__(16) short lB[2][128 * 64];   // 2 x 16 KB
  const int tid = threadIdx.x;
  const int wid = tid >> 6, lane = tid & 63;
  const int orig = blockIdx.y * 16 + blockIdx.x;
  const int lg = (orig & 7) * 32 + (orig >> 3);     // bijective XCD swizzle (256%8==0)
  const int bm = (lg & 15) * 256, bn = (lg >> 4) * 128;
  const int wr = wid >> 1, wc = wid & 1;            // 4M x 2N wave grid
  const int r = lane & 15, kq = lane >> 4, r7 = lane & 7;

  int aoff[4], boff[2], albase[4], blbase[2];
#pragma unroll
  for (int j = 0; j < 4; ++j) {
    int c = j * 512 + wid * 64 + lane;
    int row = c >> 3, ch = c & 7;
    aoff[j] = (bm + row) * Kld + (ch ^ (row & 7)) * 8;
    albase[j] = (j * 512 + wid * 64) * 16;
  }
#pragma unroll
  for (int j = 0; j < 2; ++j) {
    int c = j * 512 + wid * 64 + lane;
    int row = c >> 3, ch = c & 7;
    boff[j] = (bn + row) * Kld + (ch ^ (row & 7)) * 8;
    blbase[j] = (j * 512 + wid * 64) * 16;
  }

#define STG_A(k0, buf, j) gload_lds16(A + aoff[j] + (k0), (char*)&lA[(buf)][0] + albase[j])
#define STG_B(k0, buf, j) gload_lds16(Bt + boff[j] + (k0), (char*)&lB[(buf)][0] + blbase[j])
#define RD_A(AF, MH, KK)                                                        \
  _Pragma("unroll")                                                             \
  for (int m2 = 0; m2 < 2; ++m2)                                                \
    AF[m2] = *(const short8*)&As[(wr * 64 + (MH) * 32 + m2 * 16 + r) * 64       \
                                 + (((KK) * 4 + kq) ^ r7) * 8];
#define RD_B(KK)                                                                \
  _Pragma("unroll")                                                             \
  for (int nf = 0; nf < 4; ++nf)                                                \
    bfr[KK][nf] = *(const short8*)&Bs[(wc * 64 + nf * 16 + r) * 64              \
                                      + (((KK) * 4 + kq) ^ r7) * 8];
#define PH_MFMA(AF, MH, KK)                                                     \
  __builtin_amdgcn_s_setprio(1);                                                \
  _Pragma("unroll")                                                             \
  for (int m2 = 0; m2 < 2; ++m2)                                                \
    _Pragma("unroll")                                                           \
    for (int nf = 0; nf < 4; ++nf)                                              \
      acc[(MH) * 2 + m2][nf] = __builtin_amdgcn_mfma_f32_16x16x32_bf16(         \
          AF[m2], bfr[KK][nf], acc[(MH) * 2 + m2][nf], 0, 0, 0);                \
  __builtin_amdgcn_s_setprio(0);

  f32x4 acc[4][4];
  const f32x4 zero = {0.f, 0.f, 0.f, 0.f};
#pragma unroll
  for (int i = 0; i < 4; ++i)
#pragma unroll
    for (int j = 0; j < 4; ++j) acc[i][j] = zero;

  // prologue: A(0) 4, B(0) 2, B(1) 2; wait A0+B0 (leave B1's 2 in flight)
#pragma unroll
  for (int j = 0; j < 4; ++j) STG_A(0, 0, j);
#pragma unroll
  for (int j = 0; j < 2; ++j) STG_B(0, 0, j);
#pragma unroll
  for (int j = 0; j < 2; ++j) STG_B(64, 1, j);
  asm volatile("s_waitcnt vmcnt(2)" ::: "memory");
  block_barrier();

#pragma unroll 1
  for (int t = 0; t < nt; ++t) {
    const int cur = t & 1, nxt = cur ^ 1;
    const short* As = &lA[cur][0];
    const short* Bs = &lB[cur][0];
    const int kA = (t + 1) * 64, kB = (t + 2) * 64;
    const bool sA = (t + 1 < nt), sB = (t + 2 < nt);
    short8 bfr[2][4];
    short8 af[2];

    // p0 (kk0, mh0): B(kk0) + A(mh0,kk0); stage A(t+1) half 0
    RD_B(0)
    RD_A(af, 0, 0)
    if (sA) { STG_A(kA, nxt, 0); STG_A(kA, nxt, 1); }
    block_barrier();
    PH_MFMA(af, 0, 0)
    block_barrier();

    // p1 (kk1, mh0): B(kk1) + A(mh0,kk1); stage A(t+1) half 1
    RD_B(1)
    RD_A(af, 0, 1)
    if (sA) { STG_A(kA, nxt, 2); STG_A(kA, nxt, 3); }
    block_barrier();
    PH_MFMA(af, 0, 1)
    block_barrier();

    // p2 (kk0, mh1): stage B(t+2) half 0 (lB[cur] reads retired by p1)
    RD_A(af, 1, 0)
    if (sB) STG_B(kB, cur, 0);
    block_barrier();
    PH_MFMA(af, 1, 0)
    block_barrier();

    // p3 (kk1, mh1): stage B(t+2) half 1; boundary vmcnt
    RD_A(af, 1, 1)
    if (sB) STG_B(kB, cur, 1);
    block_barrier();
    PH_MFMA(af, 1, 1)
    if (t + 1 < nt) {
      if (sB) asm volatile("s_waitcnt vmcnt(2)" ::: "memory");  // A(t+1),B(t+1) landed
      else    asm volatile("s_waitcnt vmcnt(0)" ::: "memory");
    }
    block_barrier();
  }
#undef STG_A
#undef STG_B
#undef RD_A
#undef RD_B
#undef PH_MFMA

  // epilogue: y fp32 + bias, coalesced 64 B runs per quarter-wave
#pragma unroll
  for (int mf = 0; mf < 4; ++mf)
#pragma unroll
    for (int nf = 0; nf < 4; ++nf) {
      int n = bn + wc * 64 + nf * 16 + r;
      float bv = bias[n];
#pragma unroll
      for (int i = 0; i < 4; ++i) {
        int m = bm + wr * 64 + mf * 16 + kq * 4 + i;
        y[(size_t)m * 2048 + n] = acc[mf][nf][i] + bv;
      }
    }
}

// ---------------- causal flash attention v8: swapped QK^T (T12) --------------
// (unchanged from round 14)
__global__ __launch_bounds__(256) void k_attn(const u16* __restrict__ qh,
                                              const u16* __restrict__ kh,
                                              const u16* __restrict__ vt,
                                              u16* __restrict__ out) {
  __shared__ __align__(16) short lK[2][64 * 128];   // 32 KB
  __shared__ __align__(16) short lV[2][128 * 64];   // 32 KB
  __shared__ __align__(16) short lP[128 * 64];      // 16 KB (wave-private rows)
  const int tid = threadIdx.x, wid = tid >> 6, lane = tid & 63;
  const int id = blockIdx.x;
  const int jr = id & 15;
  const int J = (id < 256) ? jr : 15 - jr;
  const int h = (id >> 4) & 15, b = id >> 8;
  const int q0 = J * 128;
  const int nkt = 2 * J + 2;
  const size_t bh = (size_t)b * 16 + h;
  const u16* qb = qh + bh * 2048 * 128;
  const u16* kb = kh + bh * 2048 * 128;
  const u16* vb = vt + bh * 128 * 2048;
  const int r = lane & 15, kq = lane >> 4;
  const int r7 = r & 7;
  const int wrow = wid * 32;                        // wave's 32-row band

  int koff[4], voff[4];
#pragma unroll
  for (int i = 0; i < 4; ++i) {
    int ci = (wid * 4 + i) * 64 + lane;
    int krow = ci >> 4, kch = ci & 15;          // K tile: 64 rows x 16 chunks(16B)
    koff[i] = krow * 128 + ((kch ^ (krow & 7)) * 8);
    int vrow = ci >> 3, vch = ci & 7;           // V tile: 128 rows x 8 chunks(16B)
    voff[i] = vrow * 2048 + ((vch ^ (vrow & 7)) * 8);
  }

  // Q fragments (2 mf bands x 4 k-slices), q pre-scaled
  short8 qa[2][4];
#pragma unroll
  for (int mf = 0; mf < 2; ++mf)
#pragma unroll
    for (int kk = 0; kk < 4; ++kk)
      qa[mf][kk] = *(const short8*)(qb + (size_t)(q0 + wrow + mf * 16 + r) * 128 + kk * 32 + kq * 8);

  f32x4 O[2][8];
  const f32x4 zero = {0.f, 0.f, 0.f, 0.f};
#pragma unroll
  for (int mf = 0; mf < 2; ++mf)
#pragma unroll
    for (int nf = 0; nf < 8; ++nf) O[mf][nf] = zero;
  float lp[2] = {0.f, 0.f};   // lane-local row-sum partials (q-row = mf*16+r)

  // prologue stage tile 0 -> buf 0
#pragma unroll
  for (int i = 0; i < 4; ++i) {
    gload_lds16(kb + koff[i], (char*)&lK[0][0] + (wid * 4 + i) * 1024);
    gload_lds16(vb + voff[i], (char*)&lV[0][0] + (wid * 4 + i) * 1024);
  }

#pragma unroll 1
  for (int kt = 0; kt < nkt; ++kt) {
    const int cur = kt & 1;
    if (kt + 1 < nkt) {
      const size_t kbase = (size_t)(kt + 1) * 8192, vbase = (size_t)(kt + 1) * 64;
#pragma unroll
      for (int i = 0; i < 4; ++i) {
        gload_lds16(kb + kbase + koff[i], (char*)&lK[cur ^ 1][0] + (wid * 4 + i) * 1024);
        gload_lds16(vb + vbase + voff[i], (char*)&lV[cur ^ 1][0] + (wid * 4 + i) * 1024);
      }
      asm volatile("s_waitcnt vmcnt(8)" ::: "memory");  // tile kt landed; kt+1 in flight
    } else {
      asm volatile("s_waitcnt vmcnt(0)" ::: "memory");
    }
    block_barrier();

    // S^T = K @ Q^T : S[mf][nf][i] = score(q-row q0+wrow+mf*16+r,
    //                                      key kt*64+nf*16+kq*4+i)
    f32x4 S[2][4];
#pragma unroll
    for (int mf = 0; mf < 2; ++mf)
#pragma unroll
      for (int nf = 0; nf < 4; ++nf) S[mf][nf] = zero;
#pragma unroll
    for (int kk = 0; kk < 4; ++kk) {
      short8 kf[4];
#pragma unroll
      for (int nf = 0; nf < 4; ++nf)
        kf[nf] = *(const short8*)&lK[cur][(nf * 16 + r) * 128 + ((kk * 4 + kq) ^ r7) * 8];
      __builtin_amdgcn_s_setprio(1);
#pragma unroll
      for (int mf = 0; mf < 2; ++mf)
#pragma unroll
        for (int nf = 0; nf < 4; ++nf)
          S[mf][nf] = __builtin_amdgcn_mfma_f32_16x16x32_bf16(kf[nf], qa[mf][kk], S[mf][nf], 0, 0, 0);
      __builtin_amdgcn_s_setprio(0);
    }

    // P = exp2(S) un-normalized; pack pairs via cvt_pk; 8 b64 LDS writes.
    const bool diag = (kt >= nkt - 2);
#pragma unroll
    for (int mf = 0; mf < 2; ++mf) {
      const int rl = wrow + mf * 16 + r;
#pragma unroll
      for (int nf = 0; nf < 4; ++nf) {
        float pv4[4];
#pragma unroll
        for (int i = 0; i < 4; ++i) {
          float pv = exp2f(S[mf][nf][i]);
          if (diag) {
            int kg = kt * 64 + nf * 16 + kq * 4 + i;
            int qg = q0 + wrow + mf * 16 + r;
            pv = (kg > qg) ? 0.f : pv;
          }
          lp[mf] += pv;
          pv4[i] = pv;
        }
        unsigned d0, d1;
        asm("v_cvt_pk_bf16_f32 %0, %1, %2" : "=v"(d0) : "v"(pv4[0]), "v"(pv4[1]));
        asm("v_cvt_pk_bf16_f32 %0, %1, %2" : "=v"(d1) : "v"(pv4[2]), "v"(pv4[3]));
        int g = (nf * 4 + kq) ^ (r7 << 1);
        *(uint2*)((char*)lP + rl * 128 + g * 8) = make_uint2(d0, d1);
      }
    }

    // O += P @ V^T  (P read back per 8-key granule pair, swizzle-matched)
#pragma unroll
    for (int kk = 0; kk < 2; ++kk) {
      short8 pa[2];
#pragma unroll
      for (int mf = 0; mf < 2; ++mf) {
        int rl = wrow + mf * 16 + r;
        int g = (kk * 8 + kq * 2) ^ (r7 << 1);
        pa[mf] = *(const short8*)((const char*)lP + rl * 128 + g * 8);
      }
#pragma unroll
      for (int nf = 0; nf < 8; ++nf) {
        short8 vf = *(const short8*)&lV[cur][(nf * 16 + r) * 64 + ((kk * 4 + kq) ^ r7) * 8];
        __builtin_amdgcn_s_setprio(1);
#pragma unroll
        for (int mf = 0; mf < 2; ++mf)
          O[mf][nf] = __builtin_amdgcn_mfma_f32_16x16x32_bf16(pa[mf], vf, O[mf][nf], 0, 0, 0);
        __builtin_amdgcn_s_setprio(0);
      }
    }
    asm volatile("s_waitcnt lgkmcnt(0)" ::: "memory");
    block_barrier();  // all reads done before next stage overwrites
  }

  // finalize: reduce row sums across kq groups (lanes r, r+16, r+32, r+48)
#pragma unroll
  for (int mf = 0; mf < 2; ++mf) {
    float v = lp[mf];
    v += __shfl_xor(v, 16);
    v += __shfl_xor(v, 32);
    lp[mf] = v;               // all lanes now hold sum for q-row wrow+mf*16+r
  }
  // O layout: q-row = wrow+mf*16+kq*4+i, d = nf*16+r -> fetch inv via shfl
#pragma unroll
  for (int mf = 0; mf < 2; ++mf) {
    float inv[4];
#pragma unroll
    for (int i = 0; i < 4; ++i)
      inv[i] = 1.f / __shfl(lp[mf], kq * 4 + i, 16);
#pragma unroll
    for (int nf = 0; nf < 8; ++nf)
#pragma unroll
      for (int i = 0; i < 4; ++i) {
        int qg = q0 + wrow + mf * 16 + kq * 4 + i;
        out[(size_t)(b * 2048 + qg) * 2048 + h * 128 + nf * 16 + r] = f2bf(O[mf][nf][i] * inv[i]);
      }
  }
}

extern "C" void kernel_launch(void* const* d_in, const int* in_sizes, int n_in,
                              void* d_out, int out_size, void* d_ws, size_t ws_size,
                              hipStream_t stream) {
  const float* x      = (const float*)d_in[0];
  const float* W_attn = (const float*)d_in[1];
  const float* b_attn = (const float*)d_in[2];
  const float* W_proj = (const float*)d_in[3];
  const float* b_proj = (const float*)d_in[4];
  float* y = (float*)d_out;

  // workspace carve-up (bf16 buffers), total 160 MB
  u16* xb     = (u16*)d_ws;                      // [4096][2048]   MB  0-16
  u16* wqkvT  = xb     + (size_t)4096 * 2048;    // [6144][2048]   MB 16-40
  u16* wprojT = wqkvT  + (size_t)6144 * 2048;    // [2048][2048]   MB 40-48
  u16* qkv    = wprojT + (size_t)2048 * 2048;    // (free region)  MB 48-96
  u16* qh     = qkv    + (size_t)4096 * 6144;    // [32][2048][128] 96-112
  u16* kh     = qh     + (size_t)4096 * 2048;    //               112-128
  u16* vt     = kh     + (size_t)4096 * 2048;    // [32][128][2048] 128-144
  u16* attout = vt     + (size_t)4096 * 2048;    // [4096][2048]  144-160
  if (ws_size < (size_t)83886080 * 2) return;    // need 160 MB

  // free-region alias: RoPE table (1 MB, used only by k_gemmqkv)
  float* rtab = (float*)qkv;

  k_prep<<<25088, 256, 0, stream>>>(x, xb, W_attn, wqkvT, W_proj, wprojT, rtab, rtab + 131072);
  k_gemmqkv<<<dim3(16, 24), 512, 0, stream>>>(xb, wqkvT, b_attn, qh, kh, vt, rtab);
  k_attn<<<512, 256, 0, stream>>>(qh, kh, vt, attout);
  k_proj<<<dim3(16, 16), 512, 0, stream>>>(attout, wprojT, b_proj, y);
}